// Round 1
// baseline (286.999 us; speedup 1.0000x reference)
//
#include <hip/hip_runtime.h>
#include <hip/hip_bf16.h>

#define BB 64
#define SS 400
#define HH 512
#define EE 300
#define VV 50000
#define KD 812     // E+H (LSTM input width)
#define KG 1324    // 2H+E (gen_in width)
#define KC 1024    // 2H (out_cat width)
#define BV (BB*VV)

typedef __attribute__((ext_vector_type(8))) short bf16x8;
typedef __attribute__((ext_vector_type(4))) float f32x4;

// ---- workspace layout (float offsets) ----
#define WS_SCORE 0                       // [B*S]
#define WS_W     25600                   // [B*S]
#define WS_DINT  51200                   // [1324][64]  rows: 0..299 xe, 300..811 ctx, 812..1323 h_prev
#define WS_CTX   135936                  // [64][512]
#define WS_HNEW  168704                  // [64][512]
#define WS_GA    201472                  // [2048][64]
#define WS_GB    332544                  // [2048][64]
#define WS_PGEN  463616                  // [64]
#define WS_ABF   463744                  // ushort region [64][1024] bf16 out_cat (byte 1854976, 16B aligned)

__device__ __forceinline__ float sigm(float x){ return 1.f/(1.f+__expf(-x)); }
__device__ __forceinline__ float ftanh(float x){
  x = fminf(fmaxf(x,-15.f),15.f);
  float e = __expf(2.f*x);
  return (e-1.f)/(e+1.f);
}
__device__ __forceinline__ unsigned short f2bf(float f){
  unsigned int u = __builtin_bit_cast(unsigned int, f);
  u += 0x7fffu + ((u>>16)&1u);      // round-to-nearest-even
  return (unsigned short)(u>>16);
}

// K0: embedding gather -> dinT rows [0,300); h_prev transpose -> dinT rows [812,1324)
__global__ __launch_bounds__(256) void k_prep(const int* __restrict__ x,
    const float* __restrict__ emb, const float* __restrict__ h0,
    float* __restrict__ dinT)
{
  int n = blockIdx.x*256 + threadIdx.x;     // 203*256 == 19200+32768 exactly
  if (n < BB*EE){
    int b = n/EE, e = n - b*EE;
    dinT[e*BB + b] = emb[(size_t)x[b]*EE + e];
  } else {
    int m = n - BB*EE;
    int b = m >> 9, h = m & (HH-1);
    dinT[(KD + h)*BB + b] = h0[b*HH + h];
  }
}

// K1: score[b,s] = V_w . tanh(enc[b,s,:] + h_prev[b,:]) + V_b   (one wave per (b,s))
__global__ __launch_bounds__(256) void k_score(const float* __restrict__ enc,
    const float* __restrict__ h0, const float* __restrict__ Vw,
    const float* __restrict__ Vb, float* __restrict__ score)
{
  int wv = threadIdx.x >> 6, lane = threadIdx.x & 63;
  int pair = blockIdx.x*4 + wv;             // 6400*4 == 25600 exactly
  int b = pair / SS;
  int i0 = lane*8;
  const float4* ep = (const float4*)(enc + (size_t)pair*HH + i0);
  const float4* hp = (const float4*)(h0 + b*HH + i0);
  const float4* vp = (const float4*)(Vw + i0);
  float4 e0 = ep[0], e1 = ep[1];
  float4 hv0 = hp[0], hv1 = hp[1];
  float4 v0 = vp[0], v1 = vp[1];
  float sum = ftanh(e0.x+hv0.x)*v0.x + ftanh(e0.y+hv0.y)*v0.y
            + ftanh(e0.z+hv0.z)*v0.z + ftanh(e0.w+hv0.w)*v0.w
            + ftanh(e1.x+hv1.x)*v1.x + ftanh(e1.y+hv1.y)*v1.y
            + ftanh(e1.z+hv1.z)*v1.z + ftanh(e1.w+hv1.w)*v1.w;
  #pragma unroll
  for (int off=32; off; off>>=1) sum += __shfl_xor(sum, off);
  if (lane==0) score[pair] = sum + Vb[0];
}

// K2+K3: per-b softmax over S, then ctx[b,:] = sum_s w*enc[b,s,:]; also write ctx^T into dinT
__global__ __launch_bounds__(256) void k_softmax_ctx(const float* __restrict__ enc,
    const float* __restrict__ score, float* __restrict__ wout,
    float* __restrict__ ctx, float* __restrict__ dinT)
{
  __shared__ float red[256];
  __shared__ float wl[SS];
  int b = blockIdx.x, t = threadIdx.x;
  float v1 = score[b*SS + t];
  float v2 = (t < SS-256) ? score[b*SS + t + 256] : -1e30f;
  red[t] = fmaxf(v1, v2);
  __syncthreads();
  for (int o=128; o; o>>=1){ if (t<o) red[t] = fmaxf(red[t], red[t+o]); __syncthreads(); }
  float mx = red[0];
  __syncthreads();
  float e1 = __expf(v1 - mx);
  float e2 = (t < SS-256) ? __expf(v2 - mx) : 0.f;
  red[t] = e1 + e2;
  __syncthreads();
  for (int o=128; o; o>>=1){ if (t<o) red[t] += red[t+o]; __syncthreads(); }
  float inv = 1.f/red[0];
  float w1 = e1*inv;
  wl[t] = w1; wout[b*SS + t] = w1;
  if (t < SS-256){ float w2 = e2*inv; wl[t+256] = w2; wout[b*SS + t + 256] = w2; }
  __syncthreads();
  float a0 = 0.f, a1 = 0.f;
  const float* ebase = enc + (size_t)b*SS*HH;
  #pragma unroll 4
  for (int s=0; s<SS; ++s){
    float wg = wl[s];
    a0 += wg * ebase[s*HH + t];
    a1 += wg * ebase[s*HH + t + 256];
  }
  ctx[b*HH + t]       = a0;
  ctx[b*HH + t + 256] = a1;
  dinT[(EE + t)*BB + b]       = a0;
  dinT[(EE + t + 256)*BB + b] = a1;
}

// K4: gates^T halves. wave handles 4 j-rows; lane = batch. half0: W_ih over k<812, half1: W_hh.
__global__ __launch_bounds__(256) void k_gates(const float* __restrict__ Wih,
    const float* __restrict__ Whh, const float* __restrict__ dinT,
    float* __restrict__ ga, float* __restrict__ gb)
{
  int lane = threadIdx.x & 63;
  int wg = blockIdx.x*4 + (threadIdx.x >> 6);       // 0..1023
  int jg   = __builtin_amdgcn_readfirstlane(wg >> 1);
  int half = __builtin_amdgcn_readfirstlane(wg & 1);
  int j0 = jg*4;
  float a0=0.f,a1=0.f,a2=0.f,a3=0.f;
  if (half == 0){
    const float* w0 = Wih + (size_t)j0*KD;
    #pragma unroll 4
    for (int k=0; k<KD; ++k){
      float d = dinT[k*BB + lane];
      a0 += w0[k]*d; a1 += w0[KD+k]*d; a2 += w0[2*KD+k]*d; a3 += w0[3*KD+k]*d;
    }
    ga[(j0+0)*BB+lane]=a0; ga[(j0+1)*BB+lane]=a1; ga[(j0+2)*BB+lane]=a2; ga[(j0+3)*BB+lane]=a3;
  } else {
    const float* w0 = Whh + (size_t)j0*HH;
    #pragma unroll 4
    for (int k=0; k<HH; ++k){
      float d = dinT[(KD+k)*BB + lane];
      a0 += w0[k]*d; a1 += w0[HH+k]*d; a2 += w0[2*HH+k]*d; a3 += w0[3*HH+k]*d;
    }
    gb[(j0+0)*BB+lane]=a0; gb[(j0+1)*BB+lane]=a1; gb[(j0+2)*BB+lane]=a2; gb[(j0+3)*BB+lane]=a3;
  }
}

// K5: LSTM cell elementwise; writes h_new/c_new to d_out, h_new to ws, bf16 out_cat
__global__ __launch_bounds__(256) void k_lstm(const float* __restrict__ c0,
    const float* __restrict__ bih, const float* __restrict__ bhh,
    const float* __restrict__ ga, const float* __restrict__ gb,
    const float* __restrict__ ctx, float* __restrict__ hnew,
    unsigned short* __restrict__ abf, float* __restrict__ out)
{
  int n = blockIdx.x*256 + threadIdx.x;   // < 32768
  int b = n & 63, h = n >> 6;
  float gi = ga[h*BB+b]          + gb[h*BB+b]          + bih[h]        + bhh[h];
  float gf = ga[(HH+h)*BB+b]     + gb[(HH+h)*BB+b]     + bih[HH+h]     + bhh[HH+h];
  float gg = ga[(2*HH+h)*BB+b]   + gb[(2*HH+h)*BB+b]   + bih[2*HH+h]   + bhh[2*HH+h];
  float go = ga[(3*HH+h)*BB+b]   + gb[(3*HH+h)*BB+b]   + bih[3*HH+h]   + bhh[3*HH+h];
  float cn = sigm(gf)*c0[b*HH+h] + sigm(gi)*ftanh(gg);
  float hn = sigm(go)*ftanh(cn);
  out[BV + b*HH + h]          = hn;
  out[BV + BB*HH + b*HH + h]  = cn;
  hnew[b*HH + h] = hn;
  abf[b*KC + h]      = f2bf(hn);
  abf[b*KC + HH + h] = f2bf(ctx[b*HH + h]);
}

// K6: p_gen[b] = sigmoid(gen_w . [ctx, h_new, xe] + gen_b)
__global__ __launch_bounds__(256) void k_pgen(const float* __restrict__ genw,
    const float* __restrict__ genb, const float* __restrict__ ctx,
    const float* __restrict__ hnew, const float* __restrict__ dinT,
    float* __restrict__ pgen)
{
  __shared__ float red[256];
  int b = blockIdx.x, t = threadIdx.x;
  float p = 0.f;
  for (int k=t; k<KG; k+=256){
    float g = genw[k];
    float v = (k < HH) ? ctx[b*HH + k]
            : (k < 2*HH) ? hnew[b*HH + k - HH]
            : dinT[(k - 2*HH)*BB + b];
    p += g*v;
  }
  red[t] = p; __syncthreads();
  for (int o=128; o; o>>=1){ if (t<o) red[t] += red[t+o]; __syncthreads(); }
  if (t==0) pgen[b] = sigm(red[0] + genb[0]);
}

// K7: out[b,v] = p_gen[b] * (out_cat[b,:] . out_w[v,:] + out_b[v])  via bf16 MFMA
// wave: 16 v-columns x all 64 b (4 M-tiles). A,B frags: lane l -> row l&15, k = 8*(l>>4)+i.
__global__ __launch_bounds__(256) void k_gemm(const float* __restrict__ out_w,
    const float* __restrict__ out_b, const unsigned short* __restrict__ abf,
    const float* __restrict__ pgen, float* __restrict__ out)
{
  int wv = threadIdx.x >> 6;
  int vt = blockIdx.x*4 + wv;
  if (vt >= VV/16) return;
  int lane = threadIdx.x & 63;
  int col = lane & 15, kg = lane >> 4;
  const float* wrow = out_w + (size_t)(vt*16 + col)*KC + kg*8;
  const unsigned short* arow = abf + col*KC + kg*8;
  f32x4 acc0 = {0.f,0.f,0.f,0.f}, acc1 = acc0, acc2 = acc0, acc3 = acc0;
  for (int k=0; k<KC; k+=32){
    float4 w0 = *(const float4*)(wrow + k);
    float4 w1 = *(const float4*)(wrow + k + 4);
    bf16x8 bfr;
    bfr[0]=(short)f2bf(w0.x); bfr[1]=(short)f2bf(w0.y);
    bfr[2]=(short)f2bf(w0.z); bfr[3]=(short)f2bf(w0.w);
    bfr[4]=(short)f2bf(w1.x); bfr[5]=(short)f2bf(w1.y);
    bfr[6]=(short)f2bf(w1.z); bfr[7]=(short)f2bf(w1.w);
    bf16x8 af0 = *(const bf16x8*)(arow + 0*16*KC + k);
    bf16x8 af1 = *(const bf16x8*)(arow + 1*16*KC + k);
    bf16x8 af2 = *(const bf16x8*)(arow + 2*16*KC + k);
    bf16x8 af3 = *(const bf16x8*)(arow + 3*16*KC + k);
    acc0 = __builtin_amdgcn_mfma_f32_16x16x32_bf16(af0, bfr, acc0, 0,0,0);
    acc1 = __builtin_amdgcn_mfma_f32_16x16x32_bf16(af1, bfr, acc1, 0,0,0);
    acc2 = __builtin_amdgcn_mfma_f32_16x16x32_bf16(af2, bfr, acc2, 0,0,0);
    acc3 = __builtin_amdgcn_mfma_f32_16x16x32_bf16(af3, bfr, acc3, 0,0,0);
  }
  float ob = out_b[vt*16 + col];
  #pragma unroll
  for (int i=0;i<4;i++){
    int b0 = 0*16 + kg*4 + i;
    int b1 = 1*16 + kg*4 + i;
    int b2 = 2*16 + kg*4 + i;
    int b3 = 3*16 + kg*4 + i;
    out[(size_t)b0*VV + vt*16 + col] = pgen[b0]*(acc0[i] + ob);
    out[(size_t)b1*VV + vt*16 + col] = pgen[b1]*(acc1[i] + ob);
    out[(size_t)b2*VV + vt*16 + col] = pgen[b2]*(acc2[i] + ob);
    out[(size_t)b3*VV + vt*16 + col] = pgen[b3]*(acc3[i] + ob);
  }
}

// K8: pointer scatter. Last-duplicate-wins (numpy assignment semantics), race-free after dedup.
__global__ __launch_bounds__(256) void k_scatter(const int* __restrict__ text,
    const float* __restrict__ w, const float* __restrict__ pgen,
    float* __restrict__ out)
{
  int n = blockIdx.x*256 + threadIdx.x;
  if (n >= BB*SS) return;
  int b = n / SS, s = n - b*SS;
  const int* trow = text + b*SS;
  int v = trow[s];
  for (int s2 = s+1; s2 < SS; ++s2)
    if (trow[s2] == v) return;          // a later duplicate overwrites this one
  out[(size_t)b*VV + v] += (1.f - pgen[b]) * w[n];
}

extern "C" void kernel_launch(void* const* d_in, const int* in_sizes, int n_in,
                              void* d_out, int out_size, void* d_ws, size_t ws_size,
                              hipStream_t stream)
{
  const int*   x    = (const int*)  d_in[0];
  const float* enc  = (const float*)d_in[1];
  const float* h0   = (const float*)d_in[2];
  const float* c0   = (const float*)d_in[3];
  const int*   text = (const int*)  d_in[4];
  const float* emb  = (const float*)d_in[6];
  const float* Vw   = (const float*)d_in[7];
  const float* Vb   = (const float*)d_in[8];
  const float* genw = (const float*)d_in[9];
  const float* genb = (const float*)d_in[10];
  const float* outw = (const float*)d_in[11];
  const float* outb = (const float*)d_in[12];
  const float* Wih  = (const float*)d_in[13];
  const float* Whh  = (const float*)d_in[14];
  const float* bih  = (const float*)d_in[15];
  const float* bhh  = (const float*)d_in[16];
  float* out = (float*)d_out;

  float* ws     = (float*)d_ws;
  float* score  = ws + WS_SCORE;
  float* wbuf   = ws + WS_W;
  float* dinT   = ws + WS_DINT;
  float* ctx    = ws + WS_CTX;
  float* hnew   = ws + WS_HNEW;
  float* ga     = ws + WS_GA;
  float* gb     = ws + WS_GB;
  float* pgen   = ws + WS_PGEN;
  unsigned short* abf = (unsigned short*)(ws + WS_ABF);

  k_prep<<<203, 256, 0, stream>>>(x, emb, h0, dinT);
  k_score<<<6400, 256, 0, stream>>>(enc, h0, Vw, Vb, score);
  k_softmax_ctx<<<64, 256, 0, stream>>>(enc, score, wbuf, ctx, dinT);
  k_gates<<<256, 256, 0, stream>>>(Wih, Whh, dinT, ga, gb);
  k_lstm<<<128, 256, 0, stream>>>(c0, bih, bhh, ga, gb, ctx, hnew, abf, out);
  k_pgen<<<64, 256, 0, stream>>>(genw, genb, ctx, hnew, dinT, pgen);
  k_gemm<<<782, 256, 0, stream>>>(outw, outb, abf, pgen, out);
  k_scatter<<<100, 256, 0, stream>>>(text, wbuf, pgen, out);
}

// Round 2
// 211.145 us; speedup vs baseline: 1.3593x; 1.3593x over previous
//
#include <hip/hip_runtime.h>
#include <hip/hip_bf16.h>

#define BB 64
#define SS 400
#define HH 512
#define EE 300
#define VV 50000
#define KD 812     // E+H (LSTM input width)
#define KG 1324    // 2H+E (gen_in width)
#define KC 1024    // 2H (out_cat width)
#define BV (BB*VV)
#define KCH 128    // gemm K-chunk

typedef __attribute__((ext_vector_type(8))) short bf16x8;
typedef __attribute__((ext_vector_type(4))) float f32x4;

// ---- workspace layout (float offsets) ----
#define WS_SCORE 0                       // [B*S]
#define WS_W     25600                   // [B*S]
#define WS_DINT  51200                   // [1324][64]
#define WS_CTX   135936                  // [64][512]
#define WS_HNEW  168704                  // [64][512]
#define WS_GA0   201472                  // [2048][64] x4 partial gate buffers
#define WS_GA1   332544
#define WS_GB0   463616
#define WS_GB1   594688
#define WS_PGEN  725760                  // [64]
#define WS_ABF   725888                  // ushort [64][1024] bf16 out_cat (byte 2903552, 16B aligned)
#define WS_PART  758656                  // [64][8][512] ctx partials

__device__ __forceinline__ float sigm(float x){ return 1.f/(1.f+__expf(-x)); }
__device__ __forceinline__ float ftanh(float x){
  x = fminf(fmaxf(x,-15.f),15.f);
  float e = __expf(2.f*x);
  return (e-1.f)/(e+1.f);
}
__device__ __forceinline__ unsigned short f2bf(float f){
  unsigned int u = __builtin_bit_cast(unsigned int, f);
  u += 0x7fffu + ((u>>16)&1u);
  return (unsigned short)(u>>16);
}

// K0: embedding gather -> dinT rows [0,300); h_prev transpose -> dinT rows [812,1324)
__global__ __launch_bounds__(256) void k_prep(const int* __restrict__ x,
    const float* __restrict__ emb, const float* __restrict__ h0,
    float* __restrict__ dinT)
{
  int n = blockIdx.x*256 + threadIdx.x;
  if (n < BB*EE){
    int b = n/EE, e = n - b*EE;
    dinT[e*BB + b] = emb[(size_t)x[b]*EE + e];
  } else {
    int m = n - BB*EE;
    int b = m >> 9, h = m & (HH-1);
    dinT[(KD + h)*BB + b] = h0[b*HH + h];
  }
}

// K1: score[b,s] = V_w . tanh(enc[b,s,:] + h_prev[b,:]) + V_b
__global__ __launch_bounds__(256) void k_score(const float* __restrict__ enc,
    const float* __restrict__ h0, const float* __restrict__ Vw,
    const float* __restrict__ Vb, float* __restrict__ score)
{
  int wv = threadIdx.x >> 6, lane = threadIdx.x & 63;
  int pair = blockIdx.x*4 + wv;
  int b = pair / SS;
  int i0 = lane*8;
  const float4* ep = (const float4*)(enc + (size_t)pair*HH + i0);
  const float4* hp = (const float4*)(h0 + b*HH + i0);
  const float4* vp = (const float4*)(Vw + i0);
  float4 e0 = ep[0], e1 = ep[1];
  float4 hv0 = hp[0], hv1 = hp[1];
  float4 v0 = vp[0], v1 = vp[1];
  float sum = ftanh(e0.x+hv0.x)*v0.x + ftanh(e0.y+hv0.y)*v0.y
            + ftanh(e0.z+hv0.z)*v0.z + ftanh(e0.w+hv0.w)*v0.w
            + ftanh(e1.x+hv1.x)*v1.x + ftanh(e1.y+hv1.y)*v1.y
            + ftanh(e1.z+hv1.z)*v1.z + ftanh(e1.w+hv1.w)*v1.w;
  #pragma unroll
  for (int off=32; off; off>>=1) sum += __shfl_xor(sum, off);
  if (lane==0) score[pair] = sum + Vb[0];
}

// K2: per (b, s-chunk): recompute softmax over full row, partial ctx over 50 s.
__global__ __launch_bounds__(256) void k_ctx(const float* __restrict__ enc,
    const float* __restrict__ score, float* __restrict__ wout,
    float* __restrict__ part)
{
  __shared__ float red[256];
  __shared__ float wl[SS];
  int b = blockIdx.x >> 3, sp = blockIdx.x & 7;
  int t = threadIdx.x;
  float v1 = score[b*SS + t];
  float v2 = (t < SS-256) ? score[b*SS + t + 256] : -1e30f;
  red[t] = fmaxf(v1, v2);
  __syncthreads();
  for (int o=128; o; o>>=1){ if (t<o) red[t] = fmaxf(red[t], red[t+o]); __syncthreads(); }
  float mx = red[0];
  __syncthreads();
  float e1 = __expf(v1 - mx);
  float e2 = (t < SS-256) ? __expf(v2 - mx) : 0.f;
  red[t] = e1 + e2;
  __syncthreads();
  for (int o=128; o; o>>=1){ if (t<o) red[t] += red[t+o]; __syncthreads(); }
  float inv = 1.f/red[0];
  float w1 = e1*inv;
  wl[t] = w1;
  if (sp==0) wout[b*SS + t] = w1;
  if (t < SS-256){
    float w2 = e2*inv;
    wl[t+256] = w2;
    if (sp==0) wout[b*SS + t + 256] = w2;
  }
  __syncthreads();
  float a0 = 0.f, a1 = 0.f;
  const float* ebase = enc + ((size_t)b*SS + sp*50)*HH;
  #pragma unroll 5
  for (int s=0; s<50; ++s){
    float wg = wl[sp*50 + s];
    a0 += wg * ebase[s*HH + t];
    a1 += wg * ebase[s*HH + t + 256];
  }
  part[(size_t)(b*8+sp)*HH + t]       = a0;
  part[(size_t)(b*8+sp)*HH + t + 256] = a1;
}

// K3: reduce 8 ctx partials; write ctx and ctx^T into dinT
__global__ __launch_bounds__(256) void k_ctx_reduce(const float* __restrict__ part,
    float* __restrict__ ctx, float* __restrict__ dinT)
{
  int b = blockIdx.x, t = threadIdx.x;
  float a0=0.f, a1=0.f;
  #pragma unroll
  for (int sp=0; sp<8; ++sp){
    a0 += part[(size_t)(b*8+sp)*HH + t];
    a1 += part[(size_t)(b*8+sp)*HH + t + 256];
  }
  ctx[b*HH + t]       = a0;
  ctx[b*HH + t + 256] = a1;
  dinT[(EE + t)*BB + b]       = a0;
  dinT[(EE + t + 256)*BB + b] = a1;
}

// K4: gate partials. 2048 waves: 512 gate-quads x 4 K-quarters.
__global__ __launch_bounds__(256) void k_gates(const float* __restrict__ Wih,
    const float* __restrict__ Whh, const float* __restrict__ dinT,
    float* __restrict__ g0, float* __restrict__ g1,
    float* __restrict__ g2, float* __restrict__ g3)
{
  int lane = threadIdx.x & 63;
  int wg = blockIdx.x*4 + (threadIdx.x >> 6);     // 0..2047
  int jg = __builtin_amdgcn_readfirstlane(wg >> 2);
  int q  = __builtin_amdgcn_readfirstlane(wg & 3);
  int j0 = jg*4;
  float a0=0.f,a1=0.f,a2=0.f,a3=0.f;
  if (q < 2){
    const float* w0 = Wih + (size_t)j0*KD;
    int k0 = q ? 406 : 0, k1 = q ? 812 : 406;
    #pragma unroll 2
    for (int k=k0; k<k1; ++k){
      float d = dinT[k*BB + lane];
      a0 += w0[k]*d; a1 += w0[KD+k]*d; a2 += w0[2*KD+k]*d; a3 += w0[3*KD+k]*d;
    }
    float* g = q ? g1 : g0;
    g[(j0+0)*BB+lane]=a0; g[(j0+1)*BB+lane]=a1; g[(j0+2)*BB+lane]=a2; g[(j0+3)*BB+lane]=a3;
  } else {
    const float* w0 = Whh + (size_t)j0*HH;
    int k0 = (q==3) ? 256 : 0, k1 = (q==3) ? 512 : 256;
    #pragma unroll 4
    for (int k=k0; k<k1; ++k){
      float d = dinT[(KD+k)*BB + lane];
      a0 += w0[k]*d; a1 += w0[HH+k]*d; a2 += w0[2*HH+k]*d; a3 += w0[3*HH+k]*d;
    }
    float* g = (q==3) ? g3 : g2;
    g[(j0+0)*BB+lane]=a0; g[(j0+1)*BB+lane]=a1; g[(j0+2)*BB+lane]=a2; g[(j0+3)*BB+lane]=a3;
  }
}

// K5: LSTM cell elementwise
__global__ __launch_bounds__(256) void k_lstm(const float* __restrict__ c0,
    const float* __restrict__ bih, const float* __restrict__ bhh,
    const float* __restrict__ g0, const float* __restrict__ g1,
    const float* __restrict__ g2, const float* __restrict__ g3,
    const float* __restrict__ ctx, float* __restrict__ hnew,
    unsigned short* __restrict__ abf, float* __restrict__ out)
{
  int n = blockIdx.x*256 + threadIdx.x;   // < 32768
  int b = n & 63, h = n >> 6;
  #define GSUM(off) (g0[(off)*BB+b] + g1[(off)*BB+b] + g2[(off)*BB+b] + g3[(off)*BB+b] + bih[off] + bhh[off])
  float gi = GSUM(h);
  float gf = GSUM(HH+h);
  float gg = GSUM(2*HH+h);
  float go = GSUM(3*HH+h);
  #undef GSUM
  float cn = sigm(gf)*c0[b*HH+h] + sigm(gi)*ftanh(gg);
  float hn = sigm(go)*ftanh(cn);
  out[BV + b*HH + h]          = hn;
  out[BV + BB*HH + b*HH + h]  = cn;
  hnew[b*HH + h] = hn;
  abf[b*KC + h]      = f2bf(hn);
  abf[b*KC + HH + h] = f2bf(ctx[b*HH + h]);
}

// K6: p_gen[b]
__global__ __launch_bounds__(256) void k_pgen(const float* __restrict__ genw,
    const float* __restrict__ genb, const float* __restrict__ ctx,
    const float* __restrict__ hnew, const float* __restrict__ dinT,
    float* __restrict__ pgen)
{
  __shared__ float red[256];
  int b = blockIdx.x, t = threadIdx.x;
  float p = 0.f;
  for (int k=t; k<KG; k+=256){
    float g = genw[k];
    float v = (k < HH) ? ctx[b*HH + k]
            : (k < 2*HH) ? hnew[b*HH + k - HH]
            : dinT[(k - 2*HH)*BB + b];
    p += g*v;
  }
  red[t] = p; __syncthreads();
  for (int o=128; o; o>>=1){ if (t<o) red[t] += red[t+o]; __syncthreads(); }
  if (t==0) pgen[b] = sigm(red[0] + genb[0]);
}

// K7: out[b,v] = pgen[b]*(out_cat . out_w[v,:] + out_b[v]).
// Block = 4 waves, one 16-col v-tile, LDS-staged bf16 weights (double buffer,
// XOR swizzle ^(row&7)<<4), wave w owns M-tile w (16 batch rows).
__global__ __launch_bounds__(256) void k_gemm(const float* __restrict__ out_w,
    const float* __restrict__ out_b, const unsigned short* __restrict__ abf,
    const float* __restrict__ pgen, float* __restrict__ out)
{
  __shared__ unsigned short wlds[2][16*KCH];   // 2 x 4096 B
  int vt = blockIdx.x;                          // 0..3124
  int t  = threadIdx.x;
  int wv = t >> 6, lane = t & 63;
  int col = lane & 15, kg = lane >> 4;
  const float* wbase = out_w + (size_t)vt*16*KC;
  const unsigned short* arow = abf + (size_t)(wv*16 + col)*KC;

  f32x4 acc = {0.f,0.f,0.f,0.f};

  // stage chunk 0
  {
    #pragma unroll
    for (int i=0;i<2;i++){
      int p = t + i*256;
      int row = p >> 5, k4 = p & 31;
      float4 f = *(const float4*)(wbase + (size_t)row*KC + k4*4);
      unsigned int r0, r1;
      asm("v_cvt_pk_bf16_f32 %0, %1, %2" : "=v"(r0) : "v"(f.x), "v"(f.y));
      asm("v_cvt_pk_bf16_f32 %0, %1, %2" : "=v"(r1) : "v"(f.z), "v"(f.w));
      int off = (row*(KCH*2) + k4*8) ^ ((row&7)<<4);
      *(uint2*)((char*)wlds[0] + off) = make_uint2(r0, r1);
    }
  }
  __syncthreads();

  for (int c=0; c<KC/KCH; ++c){
    int cur = c & 1;
    if (c < KC/KCH-1){
      int cn = c+1;
      #pragma unroll
      for (int i=0;i<2;i++){
        int p = t + i*256;
        int row = p >> 5, k4 = p & 31;
        float4 f = *(const float4*)(wbase + (size_t)row*KC + cn*KCH + k4*4);
        unsigned int r0, r1;
        asm("v_cvt_pk_bf16_f32 %0, %1, %2" : "=v"(r0) : "v"(f.x), "v"(f.y));
        asm("v_cvt_pk_bf16_f32 %0, %1, %2" : "=v"(r1) : "v"(f.z), "v"(f.w));
        int off = (row*(KCH*2) + k4*8) ^ ((row&7)<<4);
        *(uint2*)((char*)wlds[cn & 1] + off) = make_uint2(r0, r1);
      }
    }
    #pragma unroll
    for (int ks=0; ks<KCH/32; ++ks){
      int boff = (col*(KCH*2) + ks*64 + kg*16) ^ ((col&7)<<4);
      bf16x8 bfr = *(const bf16x8*)((const char*)wlds[cur] + boff);
      bf16x8 afr = *(const bf16x8*)(arow + c*KCH + ks*32 + kg*8);
      acc = __builtin_amdgcn_mfma_f32_16x16x32_bf16(afr, bfr, acc, 0,0,0);
    }
    __syncthreads();
  }

  float ob = out_b[vt*16 + col];
  #pragma unroll
  for (int i=0;i<4;i++){
    int b = wv*16 + kg*4 + i;
    out[(size_t)b*VV + vt*16 + col] = pgen[b]*(acc[i] + ob);
  }
}

// K8: pointer scatter, last-duplicate-wins.
__global__ __launch_bounds__(256) void k_scatter(const int* __restrict__ text,
    const float* __restrict__ w, const float* __restrict__ pgen,
    float* __restrict__ out)
{
  int n = blockIdx.x*256 + threadIdx.x;
  if (n >= BB*SS) return;
  int b = n / SS, s = n - b*SS;
  const int* trow = text + b*SS;
  int v = trow[s];
  for (int s2 = s+1; s2 < SS; ++s2)
    if (trow[s2] == v) return;
  out[(size_t)b*VV + v] += (1.f - pgen[b]) * w[n];
}

extern "C" void kernel_launch(void* const* d_in, const int* in_sizes, int n_in,
                              void* d_out, int out_size, void* d_ws, size_t ws_size,
                              hipStream_t stream)
{
  const int*   x    = (const int*)  d_in[0];
  const float* enc  = (const float*)d_in[1];
  const float* h0   = (const float*)d_in[2];
  const float* c0   = (const float*)d_in[3];
  const int*   text = (const int*)  d_in[4];
  const float* emb  = (const float*)d_in[6];
  const float* Vw   = (const float*)d_in[7];
  const float* Vb   = (const float*)d_in[8];
  const float* genw = (const float*)d_in[9];
  const float* genb = (const float*)d_in[10];
  const float* outw = (const float*)d_in[11];
  const float* outb = (const float*)d_in[12];
  const float* Wih  = (const float*)d_in[13];
  const float* Whh  = (const float*)d_in[14];
  const float* bih  = (const float*)d_in[15];
  const float* bhh  = (const float*)d_in[16];
  float* out = (float*)d_out;

  float* ws     = (float*)d_ws;
  float* score  = ws + WS_SCORE;
  float* wbuf   = ws + WS_W;
  float* dinT   = ws + WS_DINT;
  float* ctx    = ws + WS_CTX;
  float* hnew   = ws + WS_HNEW;
  float* ga0    = ws + WS_GA0;
  float* ga1    = ws + WS_GA1;
  float* gb0    = ws + WS_GB0;
  float* gb1    = ws + WS_GB1;
  float* pgen   = ws + WS_PGEN;
  unsigned short* abf = (unsigned short*)(ws + WS_ABF);
  float* part   = ws + WS_PART;

  k_prep<<<203, 256, 0, stream>>>(x, emb, h0, dinT);
  k_score<<<6400, 256, 0, stream>>>(enc, h0, Vw, Vb, score);
  k_ctx<<<512, 256, 0, stream>>>(enc, score, wbuf, part);
  k_ctx_reduce<<<64, 256, 0, stream>>>(part, ctx, dinT);
  k_gates<<<512, 256, 0, stream>>>(Wih, Whh, dinT, ga0, ga1, gb0, gb1);
  k_lstm<<<128, 256, 0, stream>>>(c0, bih, bhh, ga0, ga1, gb0, gb1, ctx, hnew, abf, out);
  k_pgen<<<64, 256, 0, stream>>>(genw, genb, ctx, hnew, dinT, pgen);
  k_gemm<<<3125, 256, 0, stream>>>(outw, outb, abf, pgen, out);
  k_scatter<<<100, 256, 0, stream>>>(text, wbuf, pgen, out);
}